// Round 1
// baseline (563.126 us; speedup 1.0000x reference)
//
#include <hip/hip_runtime.h>

#define NB    4096
#define KDIM  64
#define TSTEP 256
#define BT    2          // batch elements per wave
#define DTC   0.01f

// tanh(a) = (e^{2a}-1)/(e^{2a}+1), via v_exp_f32 (exp2) + v_rcp_f32
__device__ __forceinline__ float fast_tanh(float a) {
    float t = a * 2.885390082f;              // 2*log2(e) * a
    t = fminf(fmaxf(t, -126.0f), 126.0f);    // keep exp2 finite
    float E = __builtin_amdgcn_exp2f(t);
    return (E - 1.0f) * __builtin_amdgcn_rcpf(E + 1.0f);
}

__device__ __forceinline__ float fast_exp(float a) {
    return __builtin_amdgcn_exp2f(fminf(a * 1.44269504f, 126.0f));
}

__global__ __launch_bounds__(64)
void koopman_kernel(const float* __restrict__ x,
                    const float* __restrict__ Wc1, const float* __restrict__ bc1,
                    const float* __restrict__ Wc2, const float* __restrict__ bc2,
                    const float* __restrict__ Wr1, const float* __restrict__ br1,
                    const float* __restrict__ Wr2, const float* __restrict__ br2,
                    float* __restrict__ out)
{
    const int lane = threadIdx.x;            // 0..63 = output feature
    const int blk  = blockIdx.x;             // 0..NB/BT-1

    __shared__ __align__(16) float lds_y[BT][64];
    __shared__ __align__(16) float lds_u[BT][96];   // [64..95] stays zero (r-lane pad reads)

    // ---- persistent weights: lane j holds row j of stacked layer-1 (64) and
    //      padded block-diagonal layer-2 (48) in registers for the whole sequence ----
    float w1[64];
    float w2[48];
    float b1, b2;
    if (lane < 48) {
        #pragma unroll
        for (int k = 0; k < 64; ++k) w1[k] = Wc1[lane * 64 + k];
        #pragma unroll
        for (int k = 0; k < 48; ++k) w2[k] = Wc2[lane * 48 + k];
        b1 = bc1[lane];
        b2 = bc2[lane];
    } else {
        const int r = lane - 48;
        #pragma unroll
        for (int k = 0; k < 64; ++k) w1[k] = Wr1[r * 64 + k];
        #pragma unroll
        for (int k = 0; k < 48; ++k) w2[k] = (k < 16) ? Wr2[r * 16 + k] : 0.0f;
        b1 = br1[r];
        b2 = br2[r];
    }
    const int ubase = (lane < 48) ? 0 : 48;  // layer-2 input window
    const float sgn = (lane & 1) ? 1.0f : -1.0f;
    const bool  is_c = (lane < 48);

    // ---- init state ----
    float ysel[BT];
    #pragma unroll
    for (int e = 0; e < BT; ++e) {
        ysel[e] = x[(blk * BT + e) * KDIM + lane];
        lds_y[e][lane] = ysel[e];
    }
    if (lane < 32) {
        #pragma unroll
        for (int e = 0; e < BT; ++e) lds_u[e][64 + lane] = 0.0f;
    }
    __syncthreads();

    for (int t = 0; t < TSTEP; ++t) {
        // ---- layer 1: u = tanh(W1 @ y + b1), broadcast y from LDS ----
        float acc1[BT];
        #pragma unroll
        for (int e = 0; e < BT; ++e) acc1[e] = b1;
        #pragma unroll
        for (int k4 = 0; k4 < 16; ++k4) {
            #pragma unroll
            for (int e = 0; e < BT; ++e) {
                const float4 yv = *reinterpret_cast<const float4*>(&lds_y[e][k4 * 4]);
                acc1[e] += w1[k4*4+0]*yv.x + w1[k4*4+1]*yv.y
                         + w1[k4*4+2]*yv.z + w1[k4*4+3]*yv.w;
            }
        }
        #pragma unroll
        for (int e = 0; e < BT; ++e) lds_u[e][lane] = fast_tanh(acc1[e]);
        __syncthreads();

        // ---- layer 2: co/re = W2 @ u + b2 (block-diag, r-lanes zero-padded) ----
        float acc2[BT];
        #pragma unroll
        for (int e = 0; e < BT; ++e) acc2[e] = b2;
        #pragma unroll
        for (int k4 = 0; k4 < 12; ++k4) {
            #pragma unroll
            for (int e = 0; e < BT; ++e) {
                const float4 uv = *reinterpret_cast<const float4*>(&lds_u[e][ubase + k4 * 4]);
                acc2[e] += w2[k4*4+0]*uv.x + w2[k4*4+1]*uv.y
                         + w2[k4*4+2]*uv.z + w2[k4*4+3]*uv.w;
            }
        }

        // ---- pointwise update ----
        #pragma unroll
        for (int e = 0; e < BT; ++e) {
            const float co    = acc2[e];
            const float other = __shfl_xor(co, 1, 64);
            const float mu = (lane & 1) ? other : co;     // even slot of pair
            const float om = (lane & 1) ? co    : other;  // odd slot of pair
            const float scale = fast_exp(DTC * mu);
            const float sv = __sinf(DTC * om);
            const float cv = __cosf(DTC * om);
            const float c = cv * scale;
            const float s = sv * scale;
            const float yo = __shfl_xor(ysel[e], 1, 64);
            // even lane: c*y_self - s*y_partner ; odd lane: c*y_self + s*y_partner
            const float ycnew = c * ysel[e] + sgn * s * yo;
            const float yrnew = fast_exp(DTC * co) * ysel[e];
            const float ynew  = is_c ? ycnew : yrnew;
            ysel[e] = ynew;
            lds_y[e][lane] = ynew;
            out[((size_t)(blk * BT + e) * TSTEP + t) * KDIM + lane] = ynew;
        }
        __syncthreads();   // y visible for next step's layer-1 broadcast
    }
}

extern "C" void kernel_launch(void* const* d_in, const int* in_sizes, int n_in,
                              void* d_out, int out_size, void* d_ws, size_t ws_size,
                              hipStream_t stream) {
    const float* x   = (const float*)d_in[0];
    const float* Wc1 = (const float*)d_in[1];
    const float* bc1 = (const float*)d_in[2];
    const float* Wc2 = (const float*)d_in[3];
    const float* bc2 = (const float*)d_in[4];
    const float* Wr1 = (const float*)d_in[5];
    const float* br1 = (const float*)d_in[6];
    const float* Wr2 = (const float*)d_in[7];
    const float* br2 = (const float*)d_in[8];
    float* out = (float*)d_out;

    koopman_kernel<<<dim3(NB / BT), dim3(64), 0, stream>>>(
        x, Wc1, bc1, Wc2, bc2, Wr1, br1, Wr2, br2, out);
}